// Round 12
// baseline (444.781 us; speedup 1.0000x reference)
//
#include <hip/hip_runtime.h>
#include <cstddef>

#define A_  5
#define C_  12
#define RPG (C_ * A_)                 // (coil,a) planes = 60
#define TWO_PI 6.28318530717958647692f
#define NPAD 596                      // fftB array stride (R7-proven padding)

// ---------------------------------------------------------------------------
// Pipeline R11 (resubmit; R0/R3/R8 had the same infra signature, passed
// unchanged on resubmit):
//   k_zero  : zero planar out (outfr accumulates atomically)
//   k_fft1c : R7-proven 128-thread batch-4 y-FFT  -> bufA[ca][ky][x]
//   k_colfmc: R9 structure (320 thr = 5 waves, wave-synchronous register
//             FFTs, K from global) with the per-wave shuffle scratch FOLDED
//             INTO the F arrays (F[5][576] dual-purpose):
//             LDS 43.5 -> 22.5 KB  =>  ~6 blocks/CU (~25-30 waves vs R9 ~5).
//             Safety: forward's final F-stores data-depend on the last
//             scratch reads (post-read dft8 produces the stored values);
//             inverse's scratch writes data-depend on the 8 input reads.
//             Same-wave DS ops issue in order -> aliasing is race-free.
//             Mix keeps K in GLOBAL (R10 lesson: 50 K-regs spill ->
//             174us of scratch traffic), loaded 10-wide per ao.
//             2 barriers/block.
//   k_outfr : R7-proven 128-thread batch-4 ky-IFFT + conj(mps) reduce.
// R9/R10 lessons: need simultaneously (a) high resident waves, (b) zero
// spill, (c) compulsory-only traffic. This is the first variant with all 3.
// ---------------------------------------------------------------------------
__device__ float2 g_bufA[RPG * 512 * 256];  // 63 MB [ca][ky][x]
__device__ float2 g_bufB[RPG * 512 * 256];  // 63 MB [ca][ky][x]

__device__ __forceinline__ int P5(int i) { return i + 5 * (i >> 5); }
__device__ __forceinline__ int PT(int i) { return i + (i >> 3); }

__device__ __forceinline__ void build_tab(float2* tab, int t) {
    #pragma unroll
    for (int q = 0; q < 2; ++q) {
        int k = t + q * 128;
        float s, c;
        __sincosf(-TWO_PI * (float)k * (1.0f / 512.0f), &s, &c);
        tab[PT(k)] = make_float2(c, s);
    }
}

template<int DIR>
__device__ __forceinline__ float2 cmulw(float2 v, float2 w) {
    float cv = w.x, sv = (DIR < 0) ? w.y : -w.y;   // DIR=+1 -> conj(w)
    return make_float2(v.x * cv - v.y * sv, v.x * sv + v.y * cv);
}

// ---- in-register 8-point DFT (R6/R9-proven, verbatim) ----
template<int DIR>
__device__ __forceinline__ void dft8(float* xr, float* xi) {
    const float S = 0.70710678118654752f;
    float ar[4], ai[4], br[4], bi[4];
#pragma unroll
    for (int j = 0; j < 4; ++j) {
        ar[j] = xr[j] + xr[j+4]; ai[j] = xi[j] + xi[j+4];
        br[j] = xr[j] - xr[j+4]; bi[j] = xi[j] - xi[j+4];
    }
    float t;
    if (DIR < 0) {
        t = S*(br[1]+bi[1]); bi[1] = S*(bi[1]-br[1]); br[1] = t;
        t = bi[2];           bi[2] = -br[2];          br[2] = t;
        t = S*(bi[3]-br[3]); bi[3] = -S*(br[3]+bi[3]); br[3] = t;
    } else {
        t = S*(br[1]-bi[1]); bi[1] = S*(bi[1]+br[1]); br[1] = t;
        t = -bi[2];          bi[2] = br[2];           br[2] = t;
        t = -S*(br[3]+bi[3]); bi[3] = S*(br[3]-bi[3]); br[3] = t;
    }
    float c0r=ar[0]+ar[2], c0i=ai[0]+ai[2], c1r=ar[1]+ar[3], c1i=ai[1]+ai[3];
    float d0r=ar[0]-ar[2], d0i=ai[0]-ai[2], d1r, d1i;
    if (DIR < 0) { d1r =  ai[1]-ai[3]; d1i = -(ar[1]-ar[3]); }
    else         { d1r = -(ai[1]-ai[3]); d1i =  ar[1]-ar[3]; }
    xr[0]=c0r+c1r; xi[0]=c0i+c1i; xr[4]=c0r-c1r; xi[4]=c0i-c1i;
    xr[2]=d0r+d1r; xi[2]=d0i+d1i; xr[6]=d0r-d1r; xi[6]=d0i-d1i;
    c0r=br[0]+br[2]; c0i=bi[0]+bi[2]; c1r=br[1]+br[3]; c1i=bi[1]+bi[3];
    d0r=br[0]-br[2]; d0i=bi[0]-bi[2];
    if (DIR < 0) { d1r =  bi[1]-bi[3]; d1i = -(br[1]-br[3]); }
    else         { d1r = -(bi[1]-bi[3]); d1i =  br[1]-br[3]; }
    xr[1]=c0r+c1r; xi[1]=c0i+c1i; xr[5]=c0r-c1r; xi[5]=c0i-c1i;
    xr[3]=d0r+d1r; xi[3]=d0i+d1i; xr[7]=d0r-d1r; xi[7]=d0i-d1i;
}

__device__ __forceinline__ void twiddle_chain(float* vr, float* vi, float ang) {
    float s, c; __sincosf(ang, &s, &c);
    float twr = c, twi = s;
#pragma unroll
    for (int d = 1; d < 8; ++d) {
        float tr = vr[d]*twr - vi[d]*twi;
        vi[d]    = vr[d]*twi + vi[d]*twr;
        vr[d]    = tr;
        float nr = twr*c - twi*s;
        twi      = twr*s + twi*c;
        twr      = nr;
    }
}

// Wave-synchronous 512-pt FFT (R6/R9-proven, verbatim). Input: reg a holds
// X[64a + lh]. Output: reg g holds Y[64g + 8*(lh&7) + (lh>>3)].
// sre/sim: 576-float scratch, may alias the caller's F row (in-order DS).
template<int DIR>
__device__ __forceinline__ void wfft512(float* vr, float* vi,
                                        float* sre, float* sim, int lh) {
    const float sgn = (DIR < 0) ? -1.f : 1.f;
    dft8<DIR>(vr, vi);
    twiddle_chain(vr, vi, sgn * (TWO_PI/512.f) * (float)lh);
#pragma unroll
    for (int d = 0; d < 8; ++d) { sre[72*d+lh] = vr[d]; sim[72*d+lh] = vi[d]; }
    asm volatile("s_waitcnt lgkmcnt(0)" ::: "memory");
    int rb = 72*(lh>>3) + (lh&7);
#pragma unroll
    for (int e = 0; e < 8; ++e) { vr[e] = sre[rb+8*e]; vi[e] = sim[rb+8*e]; }
    dft8<DIR>(vr, vi);
    twiddle_chain(vr, vi, sgn * (TWO_PI/64.f) * (float)(lh & 7));
    int wb = 9*(lh>>3) + (lh&7);
#pragma unroll
    for (int h = 0; h < 8; ++h) { sre[72*h+wb] = vr[h]; sim[72*h+wb] = vi[h]; }
    asm volatile("s_waitcnt lgkmcnt(0)" ::: "memory");
    int rb2 = 72*(lh&7) + 9*(lh>>3);
#pragma unroll
    for (int f = 0; f < 8; ++f) { vr[f] = sre[rb2+f]; vi[f] = sim[rb2+f]; }
    dft8<DIR>(vr, vi);
}

// Batched Stockham 512-pt FFT, NB arrays, 128 threads (R7-proven, verbatim).
template<int DIR, int NB>
__device__ void fftB(float (*AR)[NPAD], float (*AI)[NPAD],
                     float (*BR)[NPAD], float (*BI)[NPAD],
                     const float2* tab, int t) {
    float (*sR)[NPAD] = AR; float (*sI)[NPAD] = AI;
    float (*dR)[NPAD] = BR; float (*dI)[NPAD] = BI;
    int Ns = 1;
    #pragma unroll
    for (int s = 0; s < 4; ++s) {
        __syncthreads();
        int m = t & (Ns - 1);
        int e1 = m << (7 - 2 * s);
        float2 w1 = tab[PT(e1)], w2 = tab[PT(2 * e1)];
        float2 w3 = make_float2(w1.x * w2.x - w1.y * w2.y,
                                w1.x * w2.y + w1.y * w2.x);
        int i0 = P5(t), i1 = P5(t + 128), i2 = P5(t + 256), i3 = P5(t + 384);
        int idxD = ((t & ~(Ns - 1)) << 2) | m;
        int o0 = P5(idxD), o1 = P5(idxD + Ns);
        int o2 = P5(idxD + 2 * Ns), o3 = P5(idxD + 3 * Ns);
        #pragma unroll
        for (int b = 0; b < NB; ++b) {
            float2 v0 = make_float2(sR[b][i0], sI[b][i0]);
            float2 v1 = cmulw<DIR>(make_float2(sR[b][i1], sI[b][i1]), w1);
            float2 v2 = cmulw<DIR>(make_float2(sR[b][i2], sI[b][i2]), w2);
            float2 v3 = cmulw<DIR>(make_float2(sR[b][i3], sI[b][i3]), w3);
            float2 t0 = make_float2(v0.x + v2.x, v0.y + v2.y);
            float2 t1 = make_float2(v0.x - v2.x, v0.y - v2.y);
            float2 t2 = make_float2(v1.x + v3.x, v1.y + v3.y);
            float2 t3 = make_float2(v1.x - v3.x, v1.y - v3.y);
            float2 y0 = make_float2(t0.x + t2.x, t0.y + t2.y);
            float2 y2 = make_float2(t0.x - t2.x, t0.y - t2.y);
            float2 y1, y3;
            if (DIR < 0) {
                y1 = make_float2(t1.x + t3.y, t1.y - t3.x);
                y3 = make_float2(t1.x - t3.y, t1.y + t3.x);
            } else {
                y1 = make_float2(t1.x - t3.y, t1.y + t3.x);
                y3 = make_float2(t1.x + t3.y, t1.y - t3.x);
            }
            dR[b][o0] = y0.x; dI[b][o0] = y0.y;
            dR[b][o1] = y1.x; dI[b][o1] = y1.y;
            dR[b][o2] = y2.x; dI[b][o2] = y2.y;
            dR[b][o3] = y3.x; dI[b][o3] = y3.y;
        }
        { auto tp = sR; sR = dR; dR = tp; }
        { auto tp = sI; sI = dI; dI = tp; }
        Ns <<= 2;
    }
    __syncthreads();
    #pragma unroll
    for (int q = 0; q < 2; ++q) {
        int j2 = t + q * 128;
        float2 w = tab[PT(j2)];
        int i0 = P5(j2), i1 = P5(j2 + 256);
        #pragma unroll
        for (int b = 0; b < NB; ++b) {
            float2 v0 = make_float2(sR[b][i0], sI[b][i0]);
            float2 tw = cmulw<DIR>(make_float2(sR[b][i1], sI[b][i1]), w);
            dR[b][i0] = v0.x + tw.x; dI[b][i0] = v0.y + tw.y;
            dR[b][i1] = v0.x - tw.x; dI[b][i1] = v0.y - tw.y;
        }
    }
    __syncthreads();
}

// ---------------------------------------------------------------------------
__global__ void k_zero(float* __restrict__ out, int n) {
    int i = blockIdx.x * 256 + threadIdx.x;
    int stride = gridDim.x * 256;
    for (; i < n; i += stride) out[i] = 0.f;
}

// ---------------------------------------------------------------------------
// Pass 1 (R7-proven, verbatim): block = (ca, x-quad), 128 threads. Modulate
// mps*x, pad y, batch-4 forward y-FFTs, write bufA[ca][ky][x0..x0+3].
// ---------------------------------------------------------------------------
__global__ void __launch_bounds__(128) k_fft1c(const float* __restrict__ xr_,
        const float* __restrict__ xi_, const float* __restrict__ mr_,
        const float* __restrict__ mi_) {
    __shared__ float AR[4][NPAD], AI[4][NPAD], BR[4][NPAD], BI[4][NPAD];
    __shared__ float2 tab[288];
    int bid = blockIdx.x;
    int ca = bid >> 6;
    int x0 = (bid & 63) << 2;
    int coil = ca / A_, a = ca % A_;
    int t = threadIdx.x;
    build_tab(tab, t);
    int xc = t & 3, yo = t >> 2;          // yo 0..31
    int xcol = x0 + xc;
    const float* xr = xr_ + a * 65536;
    const float* xi = xi_ + a * 65536;
    const float* mr = mr_ + coil * 65536;
    const float* mi = mi_ + coil * 65536;
    #pragma unroll
    for (int r = 0; r < 4; ++r) {         // zero pads y5 in [0,128)|[384,512)
        int z = yo + 32 * r;
        AR[xc][P5(z)] = 0.f;        AI[xc][P5(z)] = 0.f;
        AR[xc][P5(384 + z)] = 0.f;  AI[xc][P5(384 + z)] = 0.f;
    }
    #pragma unroll
    for (int r = 0; r < 8; ++r) {
        int y = yo + 32 * r;
        int idx = y * 256 + xcol;
        float xrv = xr[idx], xiv = xi[idx], mrv = mr[idx], miv = mi[idx];
        int p = P5(128 + y);
        AR[xc][p] = xrv * mrv - xiv * miv;
        AI[xc][p] = xrv * miv + xiv * mrv;
    }
    fftB<-1, 4>(AR, AI, BR, BI, tab, t);
    float2* o = g_bufA + (size_t)ca * 131072 + x0 + xc;
    #pragma unroll
    for (int rr = 0; rr < 16; ++rr) {
        int ky = yo + 32 * rr;
        int p = P5(ky);
        o[(size_t)ky * 256] = make_float2(BR[xc][p], BI[xc][p]);
    }
}

// ---------------------------------------------------------------------------
// Pass 2 R11: per (coil,ky), 320 threads = 5 waves, 2 barriers.
//   fwd : wave w register-FFTs row ain=w; scratch = F[w] itself; final
//         natural-order store lands in F[w][kx].
//   mix : threads 0..255 own kx = {t, t+256}; K from global (native layout,
//         coalesced, XCD-pinned), loaded 10-wide per ao; G in place.
//   inv : wave w register-IFFTs ao=w (input read before scratch reuse,
//         in-order DS), natural-order out, coalesced row stores.
// LDS: F only = 2 * 5 * 576 * 4B = 22.5 KB  ->  ~6 blocks/CU.
// ---------------------------------------------------------------------------
__global__ void __launch_bounds__(320) k_colfmc(const float* __restrict__ kr,
                                                const float* __restrict__ ki) {
    __shared__ float FRe[A_][576], FIm[A_][576];
    int b = blockIdx.x;
    int xcd = b & 7, s = b >> 3;          // bijective XCD-cluster swizzle
    int v = s / 96, wv = s % 96;
    int u = xcd + (v << 3);               // ky-octet 0..63
    int coil = wv % C_;
    int ky = (u << 3) + (wv / C_);
    int t = threadIdx.x;
    int w = t >> 6, L = t & 63;
    int sig = ((L & 7) << 3) | (L >> 3);

    // ---- forward: wave w handles ain = w; scratch aliases F[w] ----
    {
        const float2* row = g_bufA + (size_t)(coil * A_ + w) * 131072 +
                            ((size_t)ky << 8);
        float vr[8], vi[8];
        #pragma unroll
        for (int r = 0; r < 8; ++r) { vr[r] = 0.f; vi[r] = 0.f; }
        #pragma unroll
        for (int r = 2; r < 6; ++r) {     // x5 = 64r + L in [128,384)
            float2 vv = row[((r - 2) << 6) + L];
            vr[r] = vv.x; vi[r] = vv.y;
        }
        wfft512<-1>(vr, vi, FRe[w], FIm[w], L);  // out: kx = 64g + sig
        #pragma unroll
        for (int g = 0; g < 8; ++g) {
            int kx = (g << 6) + sig;
            FRe[w][kx] = vr[g]; FIm[w][kx] = vi[g];
        }
    }
    __syncthreads();

    // ---- mix: G[ao][kx] = scale * sum_ain K[ao][ain][ky][kx] * F[ain][kx] ----
    const float scale = 4.0f / 262144.0f; // OVERSAMP^2 / (Hp*Wp)
    if (t < 256) {
        size_t kyb = (size_t)ky << 9;
        #pragma unroll
        for (int h = 0; h < 2; ++h) {
            int kx = t + (h << 8);
            float fr[A_], fi[A_];
            #pragma unroll
            for (int ain = 0; ain < A_; ++ain) {
                fr[ain] = FRe[ain][kx]; fi[ain] = FIm[ain][kx];
            }
            float gr[A_], gi[A_];
            #pragma unroll
            for (int ao = 0; ao < A_; ++ao) {
                float kre[A_], kim[A_];
                #pragma unroll
                for (int ain = 0; ain < A_; ++ain) {     // 10 loads in flight
                    size_t idx = ((size_t)(ao * A_ + ain) << 18) + kyb + kx;
                    kre[ain] = kr[idx]; kim[ain] = ki[idx];
                }
                float ar = 0.f, ai = 0.f;
                #pragma unroll
                for (int ain = 0; ain < A_; ++ain) {
                    ar += kre[ain] * fr[ain] - kim[ain] * fi[ain];
                    ai += kre[ain] * fi[ain] + kim[ain] * fr[ain];
                }
                gr[ao] = scale * ar; gi[ao] = scale * ai;
            }
            #pragma unroll
            for (int ao = 0; ao < A_; ++ao) {
                FRe[ao][kx] = gr[ao]; FIm[ao][kx] = gi[ao];
            }
        }
    }
    __syncthreads();

    // ---- inverse: wave w handles ao = w; scratch aliases F[w] ----
    {
        float vr[8], vi[8];
        #pragma unroll
        for (int r = 0; r < 8; ++r) {     // reads retire before scratch writes
            int kx = (r << 6) + sig;
            vr[r] = FRe[w][kx]; vi[r] = FIm[w][kx];
        }
        wfft512<1>(vr, vi, FRe[w], FIm[w], sig); // natural x5 = 64g + L
        float2* oB = g_bufB + (size_t)(coil * A_ + w) * 131072 +
                     ((size_t)ky << 8);
        #pragma unroll
        for (int g = 2; g < 6; ++g)       // crop x5 in [128,384)
            oB[((g - 2) << 6) + L] = make_float2(vr[g], vi[g]);
    }
}

// ---------------------------------------------------------------------------
// Pass 3 (R7-proven, verbatim): block = (a, x-quad, coil-triplet), 128 thr.
// Batch-4 inverse ky-FFTs from bufB, crop y, conj(mps) reduce, atomicAdd.
// ---------------------------------------------------------------------------
__global__ void __launch_bounds__(128) k_outfr(const float* __restrict__ mr_,
        const float* __restrict__ mi_, float* __restrict__ out, int outFloats) {
    __shared__ float AR[4][NPAD], AI[4][NPAD], BR[4][NPAD], BI[4][NPAD];
    __shared__ float2 tab[288];
    int bid = blockIdx.x;                 // 5 * 64 * 4 = 1280
    int a = bid >> 8;
    int x0 = ((bid >> 2) & 63) << 2;
    int cg = bid & 3;
    int t = threadIdx.x;
    build_tab(tab, t);
    int xc = t & 3, yo = t >> 2;          // yo 0..31
    int xcol = x0 + xc;
    float accR[8], accI[8];
    #pragma unroll
    for (int r = 0; r < 8; ++r) { accR[r] = 0.f; accI[r] = 0.f; }
    for (int cc = 0; cc < 3; ++cc) {
        int c = cg * 3 + cc;
        const float2* src = g_bufB + (size_t)(c * A_ + a) * 131072 + xcol;
        #pragma unroll
        for (int rr = 0; rr < 16; ++rr) { // stage 512 ky per xc
            int ky = yo + 32 * rr;
            float2 vv = src[(size_t)ky * 256];
            int p = P5(ky);
            AR[xc][p] = vv.x; AI[xc][p] = vv.y;
        }
        fftB<1, 4>(AR, AI, BR, BI, tab, t);    // head barrier orders staging
        const float* mr = mr_ + c * 65536;
        const float* mi = mi_ + c * 65536;
        #pragma unroll
        for (int rr = 0; rr < 8; ++rr) {       // crop y5 in [128,384)
            int y = yo + 32 * rr;
            int p = P5(128 + y);
            float vx = BR[xc][p], vy = BI[xc][p];
            int idx = y * 256 + xcol;
            float mrv = mr[idx], miv = mi[idx];
            accR[rr] += vx * mrv + vy * miv;   // v * conj(m)
            accI[rr] += vy * mrv - vx * miv;
        }
    }
    #pragma unroll
    for (int rr = 0; rr < 8; ++rr) {
        int y = yo + 32 * rr;
        size_t r0 = (size_t)a * 65536 + (size_t)y * 256 + xcol;
        size_t i0 = 327680 + r0;
        if (r0 < (size_t)outFloats) atomicAdd(&out[r0], accR[rr]);
        if (i0 < (size_t)outFloats) atomicAdd(&out[i0], accI[rr]);
    }
}

// ---------------------------------------------------------------------------
extern "C" void kernel_launch(void* const* d_in, const int* in_sizes, int n_in,
                              void* d_out, int out_size, void* d_ws, size_t ws_size,
                              hipStream_t stream) {
    const float* xr = (const float*)d_in[0];
    const float* xi = (const float*)d_in[1];
    const float* mr = (const float*)d_in[2];
    const float* mi = (const float*)d_in[3];
    const float* kr = (const float*)d_in[4];
    const float* ki = (const float*)d_in[5];
    float* out = (float*)d_out;
    (void)d_ws; (void)ws_size; (void)n_in; (void)in_sizes;

    int nz = out_size < 655360 ? out_size : 655360;   // floats to zero
    k_zero  <<<256, 256, 0, stream>>>(out, nz);
    k_fft1c <<<RPG * 64, 128, 0, stream>>>(xr, xi, mr, mi);
    k_colfmc<<<C_ * 512, 320, 0, stream>>>(kr, ki);
    k_outfr <<<A_ * 256, 128, 0, stream>>>(mr, mi, out, out_size);
}

// Round 13
// 296.678 us; speedup vs baseline: 1.4992x; 1.4992x over previous
//
#include <hip/hip_runtime.h>
#include <cstddef>

#define A_  5
#define C_  12
#define RPG (C_ * A_)                 // (coil,a) planes = 60
#define TWO_PI 6.28318530717958647692f
#define NPAD 596                      // fftB array stride (R7-proven padding)

// ---------------------------------------------------------------------------
// Pipeline R13:
//   k_zero  : zero planar out (outfr accumulates atomically)
//   k_fft1c : R7-proven 128-thread batch-4 y-FFT  -> bufA[ca][ky][x]
//   k_colfmc: R2-pacing (sequential 128-thread Stockham FFTs -- the best
//             measured structure, 122us at 31KB) with LDS cut to ONE
//             workspace + tab = 11.8 KB by holding F spectra in registers:
//             fwd ain: stage row -> fftB -> thread t pulls its 4 outputs
//             (kx = t+128q) into F-regs (40 VGPR). After 5 ains, per ao:
//             mix G[ao][kx] from reg-F + 10-wide coalesced K loads, stage
//             G into workspace, inverse fftB, coalesced row store.
//             Residency ~12 blocks = 24 waves/CU (2.4x R2).
//   k_outfr : R7-proven 128-thread batch-4 ky-IFFT + conj(mps) reduce.
// R12 falsified the wave-FFT family (hard lgkmcnt(0) drains serialize worse
// than Stockham barriers; occupancy did NOT buy it back). R9/R12 lesson
// refined: residency helps only within the winning (Stockham) structure.
// ---------------------------------------------------------------------------
__device__ float2 g_bufA[RPG * 512 * 256];  // 63 MB [ca][ky][x]
__device__ float2 g_bufB[RPG * 512 * 256];  // 63 MB [ca][ky][x]

__device__ __forceinline__ int P5(int i) { return i + 5 * (i >> 5); }
__device__ __forceinline__ int PT(int i) { return i + (i >> 3); }

__device__ __forceinline__ void build_tab(float2* tab, int t) {
    #pragma unroll
    for (int q = 0; q < 2; ++q) {
        int k = t + q * 128;
        float s, c;
        __sincosf(-TWO_PI * (float)k * (1.0f / 512.0f), &s, &c);
        tab[PT(k)] = make_float2(c, s);
    }
}

template<int DIR>
__device__ __forceinline__ float2 cmulw(float2 v, float2 w) {
    float cv = w.x, sv = (DIR < 0) ? w.y : -w.y;   // DIR=+1 -> conj(w)
    return make_float2(v.x * cv - v.y * sv, v.x * sv + v.y * cv);
}

// Batched Stockham 512-pt FFT, NB arrays, 128 threads (R7-proven, verbatim).
template<int DIR, int NB>
__device__ void fftB(float (*AR)[NPAD], float (*AI)[NPAD],
                     float (*BR)[NPAD], float (*BI)[NPAD],
                     const float2* tab, int t) {
    float (*sR)[NPAD] = AR; float (*sI)[NPAD] = AI;
    float (*dR)[NPAD] = BR; float (*dI)[NPAD] = BI;
    int Ns = 1;
    #pragma unroll
    for (int s = 0; s < 4; ++s) {
        __syncthreads();
        int m = t & (Ns - 1);
        int e1 = m << (7 - 2 * s);
        float2 w1 = tab[PT(e1)], w2 = tab[PT(2 * e1)];
        float2 w3 = make_float2(w1.x * w2.x - w1.y * w2.y,
                                w1.x * w2.y + w1.y * w2.x);
        int i0 = P5(t), i1 = P5(t + 128), i2 = P5(t + 256), i3 = P5(t + 384);
        int idxD = ((t & ~(Ns - 1)) << 2) | m;
        int o0 = P5(idxD), o1 = P5(idxD + Ns);
        int o2 = P5(idxD + 2 * Ns), o3 = P5(idxD + 3 * Ns);
        #pragma unroll
        for (int b = 0; b < NB; ++b) {
            float2 v0 = make_float2(sR[b][i0], sI[b][i0]);
            float2 v1 = cmulw<DIR>(make_float2(sR[b][i1], sI[b][i1]), w1);
            float2 v2 = cmulw<DIR>(make_float2(sR[b][i2], sI[b][i2]), w2);
            float2 v3 = cmulw<DIR>(make_float2(sR[b][i3], sI[b][i3]), w3);
            float2 t0 = make_float2(v0.x + v2.x, v0.y + v2.y);
            float2 t1 = make_float2(v0.x - v2.x, v0.y - v2.y);
            float2 t2 = make_float2(v1.x + v3.x, v1.y + v3.y);
            float2 t3 = make_float2(v1.x - v3.x, v1.y - v3.y);
            float2 y0 = make_float2(t0.x + t2.x, t0.y + t2.y);
            float2 y2 = make_float2(t0.x - t2.x, t0.y - t2.y);
            float2 y1, y3;
            if (DIR < 0) {
                y1 = make_float2(t1.x + t3.y, t1.y - t3.x);
                y3 = make_float2(t1.x - t3.y, t1.y + t3.x);
            } else {
                y1 = make_float2(t1.x - t3.y, t1.y + t3.x);
                y3 = make_float2(t1.x + t3.y, t1.y - t3.x);
            }
            dR[b][o0] = y0.x; dI[b][o0] = y0.y;
            dR[b][o1] = y1.x; dI[b][o1] = y1.y;
            dR[b][o2] = y2.x; dI[b][o2] = y2.y;
            dR[b][o3] = y3.x; dI[b][o3] = y3.y;
        }
        { auto tp = sR; sR = dR; dR = tp; }
        { auto tp = sI; sI = dI; dI = tp; }
        Ns <<= 2;
    }
    __syncthreads();
    #pragma unroll
    for (int q = 0; q < 2; ++q) {
        int j2 = t + q * 128;
        float2 w = tab[PT(j2)];
        int i0 = P5(j2), i1 = P5(j2 + 256);
        #pragma unroll
        for (int b = 0; b < NB; ++b) {
            float2 v0 = make_float2(sR[b][i0], sI[b][i0]);
            float2 tw = cmulw<DIR>(make_float2(sR[b][i1], sI[b][i1]), w);
            dR[b][i0] = v0.x + tw.x; dI[b][i0] = v0.y + tw.y;
            dR[b][i1] = v0.x - tw.x; dI[b][i1] = v0.y - tw.y;
        }
    }
    __syncthreads();
}

// ---------------------------------------------------------------------------
__global__ void k_zero(float* __restrict__ out, int n) {
    int i = blockIdx.x * 256 + threadIdx.x;
    int stride = gridDim.x * 256;
    for (; i < n; i += stride) out[i] = 0.f;
}

// ---------------------------------------------------------------------------
// Pass 1 (R7-proven, verbatim): block = (ca, x-quad), 128 threads. Modulate
// mps*x, pad y, batch-4 forward y-FFTs, write bufA[ca][ky][x0..x0+3].
// ---------------------------------------------------------------------------
__global__ void __launch_bounds__(128) k_fft1c(const float* __restrict__ xr_,
        const float* __restrict__ xi_, const float* __restrict__ mr_,
        const float* __restrict__ mi_) {
    __shared__ float AR[4][NPAD], AI[4][NPAD], BR[4][NPAD], BI[4][NPAD];
    __shared__ float2 tab[288];
    int bid = blockIdx.x;
    int ca = bid >> 6;
    int x0 = (bid & 63) << 2;
    int coil = ca / A_, a = ca % A_;
    int t = threadIdx.x;
    build_tab(tab, t);
    int xc = t & 3, yo = t >> 2;          // yo 0..31
    int xcol = x0 + xc;
    const float* xr = xr_ + a * 65536;
    const float* xi = xi_ + a * 65536;
    const float* mr = mr_ + coil * 65536;
    const float* mi = mi_ + coil * 65536;
    #pragma unroll
    for (int r = 0; r < 4; ++r) {         // zero pads y5 in [0,128)|[384,512)
        int z = yo + 32 * r;
        AR[xc][P5(z)] = 0.f;        AI[xc][P5(z)] = 0.f;
        AR[xc][P5(384 + z)] = 0.f;  AI[xc][P5(384 + z)] = 0.f;
    }
    #pragma unroll
    for (int r = 0; r < 8; ++r) {
        int y = yo + 32 * r;
        int idx = y * 256 + xcol;
        float xrv = xr[idx], xiv = xi[idx], mrv = mr[idx], miv = mi[idx];
        int p = P5(128 + y);
        AR[xc][p] = xrv * mrv - xiv * miv;
        AI[xc][p] = xrv * miv + xiv * mrv;
    }
    fftB<-1, 4>(AR, AI, BR, BI, tab, t);
    float2* o = g_bufA + (size_t)ca * 131072 + x0 + xc;
    #pragma unroll
    for (int rr = 0; rr < 16; ++rr) {
        int ky = yo + 32 * rr;
        int p = P5(ky);
        o[(size_t)ky * 256] = make_float2(BR[xc][p], BI[xc][p]);
    }
}

// ---------------------------------------------------------------------------
// Pass 2 R13: per (coil,ky), 128 threads, ONE workspace (11.8 KB LDS).
//   fwd (x5): stage bufA row (float4, coalesced) + pads -> fftB<-1,1> ->
//             thread t pulls F[ain][q] = out[kx = t+128q] into regs (40 VGPR)
//   mix+inv (x5, per ao): for q: 10-wide coalesced K loads, G = sum K*F,
//             stage G into workspace at P5(kx); fftB<1,1>; coalesced
//             float4 row store (crop x5 in [128,384)) to bufB[ca][ky][x].
//   All handoffs cross fftB's head/tail barriers; thread-private slots only.
// K native layout, XCD-pinned swizzle (proven FETCH 56.6 MB).
// ---------------------------------------------------------------------------
__global__ void __launch_bounds__(128) k_colfmc(const float* __restrict__ kr,
                                                const float* __restrict__ ki) {
    __shared__ float AR[1][NPAD], AI[1][NPAD], BR[1][NPAD], BI[1][NPAD];
    __shared__ float2 tab[288];
    int b = blockIdx.x;
    int xcd = b & 7, s = b >> 3;          // bijective XCD-cluster swizzle
    int v = s / 96, wv = s % 96;
    int u = xcd + (v << 3);               // ky-octet 0..63
    int coil = wv % C_;
    int ky = (u << 3) + (wv / C_);
    int t = threadIdx.x;
    build_tab(tab, t);

    float FrR[A_][4], FrI[A_][4];         // F[ain][kx=t+128q] in registers

    // ---- forward: 5 sequential FFTs, results -> registers ----
    const float2* bA = g_bufA + (size_t)(coil * A_) * 131072 + ((size_t)ky << 8);
    for (int ain = 0; ain < A_; ++ain) {
        float4 row = ((const float4*)(bA + (size_t)ain * 131072))[t];
        AR[0][P5(t)] = 0.f;        AI[0][P5(t)] = 0.f;
        AR[0][P5(t + 384)] = 0.f;  AI[0][P5(t + 384)] = 0.f;
        int p0 = P5(128 + 2 * t), p1 = P5(129 + 2 * t);
        AR[0][p0] = row.x; AI[0][p0] = row.y;
        AR[0][p1] = row.z; AI[0][p1] = row.w;
        fftB<-1, 1>(AR, AI, BR, BI, tab, t);   // tail barrier inside
        #pragma unroll
        for (int q = 0; q < 4; ++q) {
            int p = P5(t + q * 128);
            FrR[ain][q] = BR[0][p];
            FrI[ain][q] = BI[0][p];
        }
        // own-slot staging next iter; fftB head barrier orders vs others
    }

    // ---- mix + inverse, per ao ----
    const float scale = 4.0f / 262144.0f; // OVERSAMP^2 / (Hp*Wp)
    size_t kyb = ((size_t)ky << 9) + t;
    for (int ao = 0; ao < A_; ++ao) {
        #pragma unroll
        for (int q = 0; q < 4; ++q) {
            int kx = t + q * 128;
            float kre[A_], kim[A_];
            #pragma unroll
            for (int ain = 0; ain < A_; ++ain) {    // 10 loads in flight
                size_t idx = ((size_t)(ao * A_ + ain) << 18) + kyb + (size_t)(q * 128);
                kre[ain] = kr[idx]; kim[ain] = ki[idx];
            }
            float gr = 0.f, gi = 0.f;
            #pragma unroll
            for (int ain = 0; ain < A_; ++ain) {
                gr += kre[ain] * FrR[ain][q] - kim[ain] * FrI[ain][q];
                gi += kre[ain] * FrI[ain][q] + kim[ain] * FrR[ain][q];
            }
            int p = P5(kx);
            AR[0][p] = scale * gr;
            AI[0][p] = scale * gi;
        }
        fftB<1, 1>(AR, AI, BR, BI, tab, t);
        int p0 = P5(128 + 2 * t), p1 = P5(129 + 2 * t);  // crop x5 in [128,384)
        float4 vv = make_float4(BR[0][p0], BI[0][p0], BR[0][p1], BI[0][p1]);
        ((float4*)(g_bufB + (size_t)(coil * A_ + ao) * 131072 +
                   ((size_t)ky << 8)))[t] = vv;
    }
}

// ---------------------------------------------------------------------------
// Pass 3 (R7-proven, verbatim): block = (a, x-quad, coil-triplet), 128 thr.
// Batch-4 inverse ky-FFTs from bufB, crop y, conj(mps) reduce, atomicAdd.
// ---------------------------------------------------------------------------
__global__ void __launch_bounds__(128) k_outfr(const float* __restrict__ mr_,
        const float* __restrict__ mi_, float* __restrict__ out, int outFloats) {
    __shared__ float AR[4][NPAD], AI[4][NPAD], BR[4][NPAD], BI[4][NPAD];
    __shared__ float2 tab[288];
    int bid = blockIdx.x;                 // 5 * 64 * 4 = 1280
    int a = bid >> 8;
    int x0 = ((bid >> 2) & 63) << 2;
    int cg = bid & 3;
    int t = threadIdx.x;
    build_tab(tab, t);
    int xc = t & 3, yo = t >> 2;          // yo 0..31
    int xcol = x0 + xc;
    float accR[8], accI[8];
    #pragma unroll
    for (int r = 0; r < 8; ++r) { accR[r] = 0.f; accI[r] = 0.f; }
    for (int cc = 0; cc < 3; ++cc) {
        int c = cg * 3 + cc;
        const float2* src = g_bufB + (size_t)(c * A_ + a) * 131072 + xcol;
        #pragma unroll
        for (int rr = 0; rr < 16; ++rr) { // stage 512 ky per xc
            int ky = yo + 32 * rr;
            float2 vv = src[(size_t)ky * 256];
            int p = P5(ky);
            AR[xc][p] = vv.x; AI[xc][p] = vv.y;
        }
        fftB<1, 4>(AR, AI, BR, BI, tab, t);    // head barrier orders staging
        const float* mr = mr_ + c * 65536;
        const float* mi = mi_ + c * 65536;
        #pragma unroll
        for (int rr = 0; rr < 8; ++rr) {       // crop y5 in [128,384)
            int y = yo + 32 * rr;
            int p = P5(128 + y);
            float vx = BR[xc][p], vy = BI[xc][p];
            int idx = y * 256 + xcol;
            float mrv = mr[idx], miv = mi[idx];
            accR[rr] += vx * mrv + vy * miv;   // v * conj(m)
            accI[rr] += vy * mrv - vx * miv;
        }
    }
    #pragma unroll
    for (int rr = 0; rr < 8; ++rr) {
        int y = yo + 32 * rr;
        size_t r0 = (size_t)a * 65536 + (size_t)y * 256 + xcol;
        size_t i0 = 327680 + r0;
        if (r0 < (size_t)outFloats) atomicAdd(&out[r0], accR[rr]);
        if (i0 < (size_t)outFloats) atomicAdd(&out[i0], accI[rr]);
    }
}

// ---------------------------------------------------------------------------
extern "C" void kernel_launch(void* const* d_in, const int* in_sizes, int n_in,
                              void* d_out, int out_size, void* d_ws, size_t ws_size,
                              hipStream_t stream) {
    const float* xr = (const float*)d_in[0];
    const float* xi = (const float*)d_in[1];
    const float* mr = (const float*)d_in[2];
    const float* mi = (const float*)d_in[3];
    const float* kr = (const float*)d_in[4];
    const float* ki = (const float*)d_in[5];
    float* out = (float*)d_out;
    (void)d_ws; (void)ws_size; (void)n_in; (void)in_sizes;

    int nz = out_size < 655360 ? out_size : 655360;   // floats to zero
    k_zero  <<<256, 256, 0, stream>>>(out, nz);
    k_fft1c <<<RPG * 64, 128, 0, stream>>>(xr, xi, mr, mi);
    k_colfmc<<<C_ * 512, 128, 0, stream>>>(kr, ki);
    k_outfr <<<A_ * 256, 128, 0, stream>>>(mr, mi, out, out_size);
}

// Round 14
// 289.836 us; speedup vs baseline: 1.5346x; 1.0236x over previous
//
#include <hip/hip_runtime.h>
#include <cstddef>

#define A_  5
#define C_  12
#define RPG (C_ * A_)                 // (coil,a) planes = 60
#define TWO_PI 6.28318530717958647692f
#define NPAD 596                      // fftB array stride (R7-proven padding)

// ---------------------------------------------------------------------------
// Pipeline R14 (R13 + batch-2 fft1c/outfr):
//   k_zero  : zero planar out (outfr accumulates atomically)
//   k_fft1c : batch-2 y-FFT (LDS 21.4 KB -> 7 blocks/CU = 14 waves, was
//             40.4 KB -> 3 blocks = 6 waves), XCD-grouped swizzle so the
//             4 x-sibling blocks of each 64B bufA line share an XCD
//             (L2 merges 16B partial-line writes -- R5 write-amp lesson).
//   k_colfmc: R13-proven (101 us): sequential Stockham, 1 workspace,
//             F spectra in registers, K native + XCD-pinned.
//   k_outfr : batch-2 ky-IFFT + conj(mps) reduce, atomicAdd into out.
// R13 confirmed the recipe: Stockham pacing + minimal LDS + registers.
// fft1c/outfr were at 6 ns/FFT vs colfmc's 1.64 (both 40.4 KB batch-4);
// this applies the same residency cure to them.
// ---------------------------------------------------------------------------
__device__ float2 g_bufA[RPG * 512 * 256];  // 63 MB [ca][ky][x]
__device__ float2 g_bufB[RPG * 512 * 256];  // 63 MB [ca][ky][x]

__device__ __forceinline__ int P5(int i) { return i + 5 * (i >> 5); }
__device__ __forceinline__ int PT(int i) { return i + (i >> 3); }

__device__ __forceinline__ void build_tab(float2* tab, int t) {
    #pragma unroll
    for (int q = 0; q < 2; ++q) {
        int k = t + q * 128;
        float s, c;
        __sincosf(-TWO_PI * (float)k * (1.0f / 512.0f), &s, &c);
        tab[PT(k)] = make_float2(c, s);
    }
}

template<int DIR>
__device__ __forceinline__ float2 cmulw(float2 v, float2 w) {
    float cv = w.x, sv = (DIR < 0) ? w.y : -w.y;   // DIR=+1 -> conj(w)
    return make_float2(v.x * cv - v.y * sv, v.x * sv + v.y * cv);
}

// Batched Stockham 512-pt FFT, NB arrays, 128 threads (R7-proven, verbatim).
template<int DIR, int NB>
__device__ void fftB(float (*AR)[NPAD], float (*AI)[NPAD],
                     float (*BR)[NPAD], float (*BI)[NPAD],
                     const float2* tab, int t) {
    float (*sR)[NPAD] = AR; float (*sI)[NPAD] = AI;
    float (*dR)[NPAD] = BR; float (*dI)[NPAD] = BI;
    int Ns = 1;
    #pragma unroll
    for (int s = 0; s < 4; ++s) {
        __syncthreads();
        int m = t & (Ns - 1);
        int e1 = m << (7 - 2 * s);
        float2 w1 = tab[PT(e1)], w2 = tab[PT(2 * e1)];
        float2 w3 = make_float2(w1.x * w2.x - w1.y * w2.y,
                                w1.x * w2.y + w1.y * w2.x);
        int i0 = P5(t), i1 = P5(t + 128), i2 = P5(t + 256), i3 = P5(t + 384);
        int idxD = ((t & ~(Ns - 1)) << 2) | m;
        int o0 = P5(idxD), o1 = P5(idxD + Ns);
        int o2 = P5(idxD + 2 * Ns), o3 = P5(idxD + 3 * Ns);
        #pragma unroll
        for (int b = 0; b < NB; ++b) {
            float2 v0 = make_float2(sR[b][i0], sI[b][i0]);
            float2 v1 = cmulw<DIR>(make_float2(sR[b][i1], sI[b][i1]), w1);
            float2 v2 = cmulw<DIR>(make_float2(sR[b][i2], sI[b][i2]), w2);
            float2 v3 = cmulw<DIR>(make_float2(sR[b][i3], sI[b][i3]), w3);
            float2 t0 = make_float2(v0.x + v2.x, v0.y + v2.y);
            float2 t1 = make_float2(v0.x - v2.x, v0.y - v2.y);
            float2 t2 = make_float2(v1.x + v3.x, v1.y + v3.y);
            float2 t3 = make_float2(v1.x - v3.x, v1.y - v3.y);
            float2 y0 = make_float2(t0.x + t2.x, t0.y + t2.y);
            float2 y2 = make_float2(t0.x - t2.x, t0.y - t2.y);
            float2 y1, y3;
            if (DIR < 0) {
                y1 = make_float2(t1.x + t3.y, t1.y - t3.x);
                y3 = make_float2(t1.x - t3.y, t1.y + t3.x);
            } else {
                y1 = make_float2(t1.x - t3.y, t1.y + t3.x);
                y3 = make_float2(t1.x + t3.y, t1.y - t3.x);
            }
            dR[b][o0] = y0.x; dI[b][o0] = y0.y;
            dR[b][o1] = y1.x; dI[b][o1] = y1.y;
            dR[b][o2] = y2.x; dI[b][o2] = y2.y;
            dR[b][o3] = y3.x; dI[b][o3] = y3.y;
        }
        { auto tp = sR; sR = dR; dR = tp; }
        { auto tp = sI; sI = dI; dI = tp; }
        Ns <<= 2;
    }
    __syncthreads();
    #pragma unroll
    for (int q = 0; q < 2; ++q) {
        int j2 = t + q * 128;
        float2 w = tab[PT(j2)];
        int i0 = P5(j2), i1 = P5(j2 + 256);
        #pragma unroll
        for (int b = 0; b < NB; ++b) {
            float2 v0 = make_float2(sR[b][i0], sI[b][i0]);
            float2 tw = cmulw<DIR>(make_float2(sR[b][i1], sI[b][i1]), w);
            dR[b][i0] = v0.x + tw.x; dI[b][i0] = v0.y + tw.y;
            dR[b][i1] = v0.x - tw.x; dI[b][i1] = v0.y - tw.y;
        }
    }
    __syncthreads();
}

// ---------------------------------------------------------------------------
__global__ void k_zero(float* __restrict__ out, int n) {
    int i = blockIdx.x * 256 + threadIdx.x;
    int stride = gridDim.x * 256;
    for (; i < n; i += stride) out[i] = 0.f;
}

// ---------------------------------------------------------------------------
// Pass 1 R14: block = (ca, x-pair), 128 threads, batch-2 (21.4 KB LDS).
// Swizzle: the 4 x-pair siblings covering one 64B bufA line get consecutive
// ids on ONE XCD: b -> xcd=b&7, s=b>>3; gq=s>>2, off=s&3; G=xcd*240+gq;
// ca=G>>5, xp=((G&31)<<2)+off. Bijective over 7680.
// ---------------------------------------------------------------------------
__global__ void __launch_bounds__(128) k_fft1c(const float* __restrict__ xr_,
        const float* __restrict__ xi_, const float* __restrict__ mr_,
        const float* __restrict__ mi_) {
    __shared__ float AR[2][NPAD], AI[2][NPAD], BR[2][NPAD], BI[2][NPAD];
    __shared__ float2 tab[288];
    int b = blockIdx.x;                   // 0..7679
    int xcd = b & 7, s = b >> 3;          // s 0..959
    int gq = s >> 2, off = s & 3;         // gq 0..239
    int G = xcd * 240 + gq;               // 0..1919 = (ca, xp4)
    int ca = G >> 5;
    int xp = ((G & 31) << 2) + off;       // 0..127
    int x0 = xp << 1;
    int coil = ca / A_, a = ca % A_;
    int t = threadIdx.x;
    build_tab(tab, t);
    int xc = t & 1, yo = t >> 1;          // yo 0..63
    int xcol = x0 + xc;
    const float* xr = xr_ + a * 65536;
    const float* xi = xi_ + a * 65536;
    const float* mr = mr_ + coil * 65536;
    const float* mi = mi_ + coil * 65536;
    #pragma unroll
    for (int r = 0; r < 2; ++r) {         // zero pads y5 in [0,128)|[384,512)
        int z = yo + (r << 6);
        AR[xc][P5(z)] = 0.f;        AI[xc][P5(z)] = 0.f;
        AR[xc][P5(384 + z)] = 0.f;  AI[xc][P5(384 + z)] = 0.f;
    }
    #pragma unroll
    for (int r = 0; r < 4; ++r) {
        int y = yo + (r << 6);
        int idx = y * 256 + xcol;
        float xrv = xr[idx], xiv = xi[idx], mrv = mr[idx], miv = mi[idx];
        int p = P5(128 + y);
        AR[xc][p] = xrv * mrv - xiv * miv;
        AI[xc][p] = xrv * miv + xiv * mrv;
    }
    fftB<-1, 2>(AR, AI, BR, BI, tab, t);
    float2* o = g_bufA + (size_t)ca * 131072 + x0 + xc;
    #pragma unroll
    for (int rr = 0; rr < 8; ++rr) {
        int ky = yo + (rr << 6);
        int p = P5(ky);
        o[(size_t)ky * 256] = make_float2(BR[xc][p], BI[xc][p]);
    }
}

// ---------------------------------------------------------------------------
// Pass 2 (R13-proven, verbatim): per (coil,ky), 128 threads, ONE workspace
// (11.8 KB LDS). F spectra in registers between fwd and mix+inv phases.
// ---------------------------------------------------------------------------
__global__ void __launch_bounds__(128) k_colfmc(const float* __restrict__ kr,
                                                const float* __restrict__ ki) {
    __shared__ float AR[1][NPAD], AI[1][NPAD], BR[1][NPAD], BI[1][NPAD];
    __shared__ float2 tab[288];
    int b = blockIdx.x;
    int xcd = b & 7, s = b >> 3;          // bijective XCD-cluster swizzle
    int v = s / 96, wv = s % 96;
    int u = xcd + (v << 3);               // ky-octet 0..63
    int coil = wv % C_;
    int ky = (u << 3) + (wv / C_);
    int t = threadIdx.x;
    build_tab(tab, t);

    float FrR[A_][4], FrI[A_][4];         // F[ain][kx=t+128q] in registers

    // ---- forward: 5 sequential FFTs, results -> registers ----
    const float2* bA = g_bufA + (size_t)(coil * A_) * 131072 + ((size_t)ky << 8);
    for (int ain = 0; ain < A_; ++ain) {
        float4 row = ((const float4*)(bA + (size_t)ain * 131072))[t];
        AR[0][P5(t)] = 0.f;        AI[0][P5(t)] = 0.f;
        AR[0][P5(t + 384)] = 0.f;  AI[0][P5(t + 384)] = 0.f;
        int p0 = P5(128 + 2 * t), p1 = P5(129 + 2 * t);
        AR[0][p0] = row.x; AI[0][p0] = row.y;
        AR[0][p1] = row.z; AI[0][p1] = row.w;
        fftB<-1, 1>(AR, AI, BR, BI, tab, t);   // tail barrier inside
        #pragma unroll
        for (int q = 0; q < 4; ++q) {
            int p = P5(t + q * 128);
            FrR[ain][q] = BR[0][p];
            FrI[ain][q] = BI[0][p];
        }
    }

    // ---- mix + inverse, per ao ----
    const float scale = 4.0f / 262144.0f; // OVERSAMP^2 / (Hp*Wp)
    size_t kyb = ((size_t)ky << 9) + t;
    for (int ao = 0; ao < A_; ++ao) {
        #pragma unroll
        for (int q = 0; q < 4; ++q) {
            int kx = t + q * 128;
            float kre[A_], kim[A_];
            #pragma unroll
            for (int ain = 0; ain < A_; ++ain) {    // 10 loads in flight
                size_t idx = ((size_t)(ao * A_ + ain) << 18) + kyb + (size_t)(q * 128);
                kre[ain] = kr[idx]; kim[ain] = ki[idx];
            }
            float gr = 0.f, gi = 0.f;
            #pragma unroll
            for (int ain = 0; ain < A_; ++ain) {
                gr += kre[ain] * FrR[ain][q] - kim[ain] * FrI[ain][q];
                gi += kre[ain] * FrI[ain][q] + kim[ain] * FrR[ain][q];
            }
            int p = P5(kx);
            AR[0][p] = scale * gr;
            AI[0][p] = scale * gi;
        }
        fftB<1, 1>(AR, AI, BR, BI, tab, t);
        int p0 = P5(128 + 2 * t), p1 = P5(129 + 2 * t);  // crop x5 in [128,384)
        float4 vv = make_float4(BR[0][p0], BI[0][p0], BR[0][p1], BI[0][p1]);
        ((float4*)(g_bufB + (size_t)(coil * A_ + ao) * 131072 +
                   ((size_t)ky << 8)))[t] = vv;
    }
}

// ---------------------------------------------------------------------------
// Pass 3 R14: block = (a, x-pair, coil-triplet), 128 threads, batch-2
// (21.4 KB LDS). Inverse ky-FFTs from bufB, crop y, conj(mps) reduce,
// atomicAdd into planar out.
// ---------------------------------------------------------------------------
__global__ void __launch_bounds__(128) k_outfr(const float* __restrict__ mr_,
        const float* __restrict__ mi_, float* __restrict__ out, int outFloats) {
    __shared__ float AR[2][NPAD], AI[2][NPAD], BR[2][NPAD], BI[2][NPAD];
    __shared__ float2 tab[288];
    int bid = blockIdx.x;                 // 5 * 128 * 4 = 2560
    int a = bid >> 9;
    int rem = bid & 511;
    int xp = rem >> 2, cg = rem & 3;
    int x0 = xp << 1;
    int t = threadIdx.x;
    build_tab(tab, t);
    int xc = t & 1, yo = t >> 1;          // yo 0..63
    int xcol = x0 + xc;
    float accR[4], accI[4];
    #pragma unroll
    for (int r = 0; r < 4; ++r) { accR[r] = 0.f; accI[r] = 0.f; }
    for (int cc = 0; cc < 3; ++cc) {
        int c = cg * 3 + cc;
        const float2* src = g_bufB + (size_t)(c * A_ + a) * 131072 + xcol;
        #pragma unroll
        for (int rr = 0; rr < 8; ++rr) {  // stage 512 ky per xc
            int ky = yo + (rr << 6);
            float2 vv = src[(size_t)ky * 256];
            int p = P5(ky);
            AR[xc][p] = vv.x; AI[xc][p] = vv.y;
        }
        fftB<1, 2>(AR, AI, BR, BI, tab, t);    // head barrier orders staging
        const float* mr = mr_ + c * 65536;
        const float* mi = mi_ + c * 65536;
        #pragma unroll
        for (int rr = 0; rr < 4; ++rr) {       // crop y5 in [128,384)
            int y = yo + (rr << 6);
            int p = P5(128 + y);
            float vx = BR[xc][p], vy = BI[xc][p];
            int idx = y * 256 + xcol;
            float mrv = mr[idx], miv = mi[idx];
            accR[rr] += vx * mrv + vy * miv;   // v * conj(m)
            accI[rr] += vy * mrv - vx * miv;
        }
    }
    #pragma unroll
    for (int rr = 0; rr < 4; ++rr) {
        int y = yo + (rr << 6);
        size_t r0 = (size_t)a * 65536 + (size_t)y * 256 + xcol;
        size_t i0 = 327680 + r0;
        if (r0 < (size_t)outFloats) atomicAdd(&out[r0], accR[rr]);
        if (i0 < (size_t)outFloats) atomicAdd(&out[i0], accI[rr]);
    }
}

// ---------------------------------------------------------------------------
extern "C" void kernel_launch(void* const* d_in, const int* in_sizes, int n_in,
                              void* d_out, int out_size, void* d_ws, size_t ws_size,
                              hipStream_t stream) {
    const float* xr = (const float*)d_in[0];
    const float* xi = (const float*)d_in[1];
    const float* mr = (const float*)d_in[2];
    const float* mi = (const float*)d_in[3];
    const float* kr = (const float*)d_in[4];
    const float* ki = (const float*)d_in[5];
    float* out = (float*)d_out;
    (void)d_ws; (void)ws_size; (void)n_in; (void)in_sizes;

    int nz = out_size < 655360 ? out_size : 655360;   // floats to zero
    k_zero  <<<256, 256, 0, stream>>>(out, nz);
    k_fft1c <<<RPG * 128, 128, 0, stream>>>(xr, xi, mr, mi);
    k_colfmc<<<C_ * 512, 128, 0, stream>>>(kr, ki);
    k_outfr <<<A_ * 256 * 2, 128, 0, stream>>>(mr, mi, out, out_size);
}